// Round 3
// baseline (1898.022 us; speedup 1.0000x reference)
//
#include <hip/hip_runtime.h>
#include <hip/hip_bf16.h>

// ---------------------------------------------------------------------------
// B=8, NT=32, NO=8, C=512, VD=1024, RD=300; No=512, Nr=2048.
// Inputs fp32. r-chain (feeds softmax logits): split-bf16 MFMA (~fp32 precise),
// fp32 intermediates. o-branch + epilogue: plain bf16 MFMA. Output fp32.
// ---------------------------------------------------------------------------

typedef __attribute__((ext_vector_type(4))) float f32x4;
typedef __attribute__((ext_vector_type(8))) short bf16x8s;

#define TILE 128
#define BKK 32
#define LDSS 40  // bf16 LDS row stride (32+8)
#define LDA 36   // f32 A-tile row stride (32+4)
#define LDB 132  // f32 B-tile row stride (128+4)

// ---------------- split-precision GEMM (fp32 in/out, ~fp32 accurate) --------
// D = act(A@B + addsrc + bias); all fp32. A:(batch,M,K) lda; B:(batch,K,N) ldb.
__global__ __launch_bounds__(256) void gemm_split(
    const float* __restrict__ A, long long sA, int lda,
    const float* __restrict__ B, long long sB, int ldb,
    float* __restrict__ D, long long sD, int ldd,
    const float* __restrict__ addsrc, long long sAdd, int ldadd,
    const float* __restrict__ bias,
    int K, int relu)
{
    __shared__ float As[TILE * LDA];  // 18 KB
    __shared__ float Bs[BKK * LDB];   // 16.5 KB

    const int tid  = threadIdx.x;
    const int lane = tid & 63;
    const int wave = tid >> 6;
    const int wm   = (wave >> 1) * 64;
    const int wn   = (wave & 1) * 64;
    const int row0 = blockIdx.y * TILE;
    const int col0 = blockIdx.x * TILE;
    const int b    = blockIdx.z;

    const float* Ab = A + (size_t)b * sA;
    const float* Bb = B + (size_t)b * sB;

    f32x4 acc[4][4];
#pragma unroll
    for (int i = 0; i < 4; ++i)
#pragma unroll
        for (int j = 0; j < 4; ++j) acc[i][j] = (f32x4){0.f, 0.f, 0.f, 0.f};

    const int quad = lane >> 4;
    const int l16  = lane & 15;

    for (int k0 = 0; k0 < K; k0 += BKK) {
        __syncthreads();
#pragma unroll
        for (int it = 0; it < 4; ++it) { // A tile 128x32 f32
            int task = tid + it * 256;
            int m = task >> 3, kq = task & 7;
            float4 val = *(const float4*)(Ab + (size_t)(row0 + m) * lda + k0 + kq * 4);
            *(float4*)(&As[m * LDA + kq * 4]) = val;
        }
#pragma unroll
        for (int it = 0; it < 4; ++it) { // B tile 32x128 f32 (not transposed)
            int task = tid + it * 256;
            int kk = task >> 5, n4 = task & 31;
            float4 val = *(const float4*)(Bb + (size_t)(k0 + kk) * ldb + col0 + n4 * 4);
            *(float4*)(&Bs[kk * LDB + n4 * 4]) = val;
        }
        __syncthreads();

        bf16x8s ah[4], al[4], bh[4], bl[4];
#pragma unroll
        for (int mt = 0; mt < 4; ++mt) {
            const float* ap = &As[(wm + mt * 16 + l16) * LDA + quad * 8];
            f32x4 v0 = *(const f32x4*)(ap);
            f32x4 v1 = *(const f32x4*)(ap + 4);
#pragma unroll
            for (int u = 0; u < 8; ++u) {
                float a = (u < 4) ? v0[u] : v1[u - 4];
                __hip_bfloat16 h = __float2bfloat16(a);
                float hf = __bfloat162float(h);
                __hip_bfloat16 l = __float2bfloat16(a - hf);
                ah[mt][u] = *(short*)&h;
                al[mt][u] = *(short*)&l;
            }
        }
#pragma unroll
        for (int nt = 0; nt < 4; ++nt) {
            int col = wn + nt * 16 + l16;
#pragma unroll
            for (int u = 0; u < 8; ++u) {
                float bval = Bs[(quad * 8 + u) * LDB + col];
                __hip_bfloat16 h = __float2bfloat16(bval);
                float hf = __bfloat162float(h);
                __hip_bfloat16 l = __float2bfloat16(bval - hf);
                bh[nt][u] = *(short*)&h;
                bl[nt][u] = *(short*)&l;
            }
        }
#pragma unroll
        for (int mt = 0; mt < 4; ++mt)
#pragma unroll
            for (int nt = 0; nt < 4; ++nt) {
                acc[mt][nt] = __builtin_amdgcn_mfma_f32_16x16x32_bf16(ah[mt], bh[nt], acc[mt][nt], 0, 0, 0);
                acc[mt][nt] = __builtin_amdgcn_mfma_f32_16x16x32_bf16(ah[mt], bl[nt], acc[mt][nt], 0, 0, 0);
                acc[mt][nt] = __builtin_amdgcn_mfma_f32_16x16x32_bf16(al[mt], bh[nt], acc[mt][nt], 0, 0, 0);
            }
    }

    float* Db = D + (size_t)b * sD;
    const float* Addb = addsrc ? addsrc + (size_t)b * sAdd : nullptr;
#pragma unroll
    for (int mt = 0; mt < 4; ++mt)
#pragma unroll
        for (int nt = 0; nt < 4; ++nt)
#pragma unroll
            for (int r = 0; r < 4; ++r) {
                int m = row0 + wm + mt * 16 + quad * 4 + r;
                int n = col0 + wn + nt * 16 + l16;
                float v = acc[mt][nt][r];
                if (Addb) v += Addb[(size_t)m * ldadd + n];
                if (bias) v += bias[n];
                if (relu && v < 0.f) v = 0.f;
                Db[(size_t)m * ldd + n] = v;
            }
}

// ---------------- plain bf16 GEMM (o-branch / epilogue) ---------------------
__global__ __launch_bounds__(256) void gemm_bf16(
    const __hip_bfloat16* __restrict__ A, long long sA, int lda,
    const __hip_bfloat16* __restrict__ B, long long sB, int ldb,
    void* __restrict__ D, long long sD, int ldd,
    const __hip_bfloat16* __restrict__ addsrc, long long sAdd, int ldadd,
    const float* __restrict__ bias,
    int K, int relu, int outF32)
{
    __shared__ __hip_bfloat16 As[TILE * LDSS];
    __shared__ __hip_bfloat16 Bs[TILE * LDSS]; // transposed: Bs[n][k]

    const int tid  = threadIdx.x;
    const int lane = tid & 63;
    const int wave = tid >> 6;
    const int wm   = (wave >> 1) * 64;
    const int wn   = (wave & 1) * 64;
    const int row0 = blockIdx.y * TILE;
    const int col0 = blockIdx.x * TILE;
    const int b    = blockIdx.z;

    const __hip_bfloat16* Ab = A + (size_t)b * sA;
    const __hip_bfloat16* Bb = B + (size_t)b * sB;

    f32x4 acc[4][4];
#pragma unroll
    for (int i = 0; i < 4; ++i)
#pragma unroll
        for (int j = 0; j < 4; ++j) acc[i][j] = (f32x4){0.f, 0.f, 0.f, 0.f};

    const int quad = lane >> 4;
    const int l16  = lane & 15;

    for (int k0 = 0; k0 < K; k0 += BKK) {
        __syncthreads();
#pragma unroll
        for (int it = 0; it < 2; ++it) {
            int task = tid + it * 256;
            int m = task >> 2, kq = task & 3;
            uint4 val = *(const uint4*)(Ab + (size_t)(row0 + m) * lda + k0 + kq * 8);
            *(uint4*)(&As[m * LDSS + kq * 8]) = val;
        }
#pragma unroll
        for (int it = 0; it < 2; ++it) {
            int task = tid + it * 256;
            int kk = task >> 4, n8 = task & 15;
            uint4 val = *(const uint4*)(Bb + (size_t)(k0 + kk) * ldb + col0 + n8 * 8);
            const __hip_bfloat16* v16 = (const __hip_bfloat16*)&val;
#pragma unroll
            for (int u = 0; u < 8; ++u)
                Bs[(n8 * 8 + u) * LDSS + kk] = v16[u];
        }
        __syncthreads();

        bf16x8s afrag[4], bfrag[4];
#pragma unroll
        for (int mt = 0; mt < 4; ++mt)
            afrag[mt] = *(const bf16x8s*)(&As[(wm + mt * 16 + l16) * LDSS + quad * 8]);
#pragma unroll
        for (int nt = 0; nt < 4; ++nt)
            bfrag[nt] = *(const bf16x8s*)(&Bs[(wn + nt * 16 + l16) * LDSS + quad * 8]);
#pragma unroll
        for (int mt = 0; mt < 4; ++mt)
#pragma unroll
            for (int nt = 0; nt < 4; ++nt)
                acc[mt][nt] = __builtin_amdgcn_mfma_f32_16x16x32_bf16(
                    afrag[mt], bfrag[nt], acc[mt][nt], 0, 0, 0);
    }

    __hip_bfloat16* Db16 = (__hip_bfloat16*)D + (size_t)b * sD;
    float*          DbF  = (float*)D + (size_t)b * sD;
    const __hip_bfloat16* Addb = addsrc ? addsrc + (size_t)b * sAdd : nullptr;
#pragma unroll
    for (int mt = 0; mt < 4; ++mt)
#pragma unroll
        for (int nt = 0; nt < 4; ++nt)
#pragma unroll
            for (int r = 0; r < 4; ++r) {
                int m = row0 + wm + mt * 16 + quad * 4 + r;
                int n = col0 + wn + nt * 16 + l16;
                float v = acc[mt][nt][r];
                if (Addb) v += __bfloat162float(Addb[(size_t)m * ldadd + n]);
                if (bias) v += bias[n];
                if (relu && v < 0.f) v = 0.f;
                if (outF32) DbF[(size_t)m * ldd + n] = v;
                else        Db16[(size_t)m * ldd + n] = __float2bfloat16(v);
            }
}

// fp32 -> bf16 converter (n divisible by 4)
__global__ void convert_kernel(const float* __restrict__ src,
                               __hip_bfloat16* __restrict__ dst, int n4)
{
    int i = blockIdx.x * blockDim.x + threadIdx.x;
    if (i >= n4) return;
    float4 v = ((const float4*)src)[i];
    __hip_bfloat16 t0 = __float2bfloat16(v.x), t1 = __float2bfloat16(v.y);
    __hip_bfloat16 t2 = __float2bfloat16(v.z), t3 = __float2bfloat16(v.w);
    ushort4 o = { *(unsigned short*)&t0, *(unsigned short*)&t1,
                  *(unsigned short*)&t2, *(unsigned short*)&t3 };
    ((ushort4*)dst)[i] = o;
}

// fp32 zero-padded copy
__global__ void padcopy_f32(const float* __restrict__ src, float* __restrict__ dst,
                            int srows, int scols, int drows, int dcols)
{
    int idx = blockIdx.x * blockDim.x + threadIdx.x;
    if (idx >= drows * dcols) return;
    int r = idx / dcols, c = idx - r * dcols;
    dst[idx] = (r < srows && c < scols) ? src[(size_t)r * scols + c] : 0.f;
}

// ---------------- fused segment attention + query-mean (fp32 q/k/v) ---------
// q/k/v: (16384,512) fp32, row = g*64 + i*8 + j.
// mode 0: segment (g,i), seq over j -> abar row g*16 + i
// mode 1: segment (g,j), seq over i -> abar row g*16 + 8 + j
__global__ __launch_bounds__(256) void attn_kernel(
    const float* __restrict__ q,
    const float* __restrict__ k,
    const float* __restrict__ v,
    __hip_bfloat16* __restrict__ abar)
{
    __shared__ float qs[8][512], ks[8][512], vs[8][512];
    __shared__ float sc[4][8][8];
    __shared__ float wb[4][8];

    const int tid  = threadIdx.x;
    const int mode = blockIdx.y;
    const int g    = blockIdx.x >> 3;
    const int idx  = blockIdx.x & 7;
    const int rowBase = g * 64;

    for (int t = tid; t < 512; t += 256) {
        int p = t >> 6, c8 = (t & 63) * 8;
        int row = (mode == 0) ? (rowBase + idx * 8 + p) : (rowBase + p * 8 + idx);
        const float* qp = q + (size_t)row * 512 + c8;
        const float* kp = k + (size_t)row * 512 + c8;
        const float* vp = v + (size_t)row * 512 + c8;
        *(float4*)(&qs[p][c8])     = *(const float4*)(qp);
        *(float4*)(&qs[p][c8 + 4]) = *(const float4*)(qp + 4);
        *(float4*)(&ks[p][c8])     = *(const float4*)(kp);
        *(float4*)(&ks[p][c8 + 4]) = *(const float4*)(kp + 4);
        *(float4*)(&vs[p][c8])     = *(const float4*)(vp);
        *(float4*)(&vs[p][c8 + 4]) = *(const float4*)(vp + 4);
    }
    __syncthreads();

    { // scores: 4 heads x 8x8
        int h = tid >> 6, l = tid & 63;
        int i = l >> 3, j = l & 7;
        const float* qrow = &qs[i][h * 128];
        const float* krow = &ks[j][h * 128];
        float s = 0.f;
#pragma unroll
        for (int d = 0; d < 128; d += 4) {
            float4 qa = *(const float4*)(qrow + d);
            float4 kb = *(const float4*)(krow + d);
            s += qa.x * kb.x + qa.y * kb.y + qa.z * kb.z + qa.w * kb.w;
        }
        sc[h][i][j] = s * 0.08838834764831845f; // 1/sqrt(128)
    }
    __syncthreads();

    if (tid < 32) { // softmax over j
        int h = tid >> 3, i = tid & 7;
        float mx = -1e30f;
#pragma unroll
        for (int j = 0; j < 8; ++j) mx = fmaxf(mx, sc[h][i][j]);
        float e[8], sum = 0.f;
#pragma unroll
        for (int j = 0; j < 8; ++j) { e[j] = __expf(sc[h][i][j] - mx); sum += e[j]; }
        float inv = 1.f / sum;
#pragma unroll
        for (int j = 0; j < 8; ++j) sc[h][i][j] = e[j] * inv;
    }
    __syncthreads();

    if (tid < 32) { // mean over queries -> per-key weight
        int h = tid >> 3, j = tid & 7;
        float s = 0.f;
#pragma unroll
        for (int i = 0; i < 8; ++i) s += sc[h][i][j];
        wb[h][j] = s * 0.125f;
    }
    __syncthreads();

    {
        int orow = g * 16 + mode * 8 + idx;
        for (int c = tid; c < 512; c += 256) {
            int h = c >> 7;
            float o = 0.f;
#pragma unroll
            for (int j = 0; j < 8; ++j) o += wb[h][j] * vs[j][c];
            abar[(size_t)orow * 512 + c] = __float2bfloat16(o);
        }
    }
}

// ---------------------------------------------------------------------------

extern "C" void kernel_launch(void* const* d_in, const int* in_sizes, int n_in,
                              void* d_out, int out_size, void* d_ws, size_t ws_size,
                              hipStream_t stream)
{
    const float* Ao   = (const float*)d_in[0];   // (8,512,512)
    const float* srco = (const float*)d_in[1];   // (4096,1024)
    const float* Ar   = (const float*)d_in[2];   // (8,2048,2048)
    const float* srcr = (const float*)d_in[3];   // (16384,300)
    const float* Wo1  = (const float*)d_in[4];   // (1024,1024)
    const float* Wo2  = (const float*)d_in[5];   // (1024,512)
    const float* Wr1  = (const float*)d_in[6];   // (300,1024)
    const float* Wr2  = (const float*)d_in[7];   // (1024,512)
    const float* Wq   = (const float*)d_in[8];
    const float* bq   = (const float*)d_in[9];
    const float* Wk   = (const float*)d_in[10];
    const float* bk   = (const float*)d_in[11];
    const float* Wv   = (const float*)d_in[12];
    const float* bv   = (const float*)d_in[13];
    const float* Wp   = (const float*)d_in[14];
    const float* bp   = (const float*)d_in[15];
    const float* We   = (const float*)d_in[16];  // (1024,512)
    const float* be   = (const float*)d_in[17];
    float* out = (float*)d_out;                  // (4096,512) fp32

    char* ws = (char*)d_ws;
    // fp32 regions (r-chain), with lifetime reuse:
    const size_t OFF_TR  = 0;            // 67.1MB: TRf; later qF(+0), ABAR(+33.5M)
    const size_t OFF_HR  = 67108864;     // 67.1MB: HRf; later kF(+0), vF(+33.5M)
    const size_t OFF_T2R = 134217728;    // 33.5MB: T2Rf; later o-branch bf16 pool
    const size_t OFF_GR  = 167772160;    // 33.5MB: GRf;  later o-branch bf16 pool
    const size_t OFF_XP  = 201326592;    // 21MB : XPf
    const size_t OFF_WP  = 222298112;    // 1.3MB: WPf    (total ~224MB)

    float* TRf  = (float*)(ws + OFF_TR);
    float* qF   = (float*)(ws + OFF_TR);
    __hip_bfloat16* ABAR = (__hip_bfloat16*)(ws + OFF_TR + 33554432);
    float* HRf  = (float*)(ws + OFF_HR);
    float* kF   = (float*)(ws + OFF_HR);
    float* vF   = (float*)(ws + OFF_HR + 33554432);
    float* T2Rf = (float*)(ws + OFF_T2R);
    float* GRf  = (float*)(ws + OFF_GR);
    float* XPf  = (float*)(ws + OFF_XP);
    float* WPf  = (float*)(ws + OFF_WP);

    // o-branch bf16 pool inside [OFF_T2R, OFF_T2R+67.1MB) — used after GR/qkv done
    __hip_bfloat16* TO    = (__hip_bfloat16*)(ws + OFF_T2R + 0);
    __hip_bfloat16* HO    = (__hip_bfloat16*)(ws + OFF_T2R + 8388608);
    __hip_bfloat16* T2O   = (__hip_bfloat16*)(ws + OFF_T2R + 16777216);
    __hip_bfloat16* CAT   = (__hip_bfloat16*)(ws + OFF_T2R + 20971520);
    __hip_bfloat16* srcoB = (__hip_bfloat16*)(ws + OFF_T2R + 29360128);
    __hip_bfloat16* AoB   = (__hip_bfloat16*)(ws + OFF_T2R + 37748736);
    __hip_bfloat16* Wo1B  = (__hip_bfloat16*)(ws + OFF_T2R + 41943040);
    __hip_bfloat16* Wo2B  = (__hip_bfloat16*)(ws + OFF_T2R + 44040192);
    __hip_bfloat16* WeB   = (__hip_bfloat16*)(ws + OFF_T2R + 45088768);
    __hip_bfloat16* WpB   = (__hip_bfloat16*)(ws + OFF_T2R + 46137344);

    dim3 blk(256);
    auto cvt = [&](const float* s, __hip_bfloat16* d, int n) {
        convert_kernel<<<dim3((n / 4 + 255) / 256), blk, 0, stream>>>(s, d, n / 4);
    };

    // ---- r-branch (split precision, fp32 data) ----
    padcopy_f32<<<dim3((16384 * 320 + 255) / 256), blk, 0, stream>>>(srcr, XPf, 16384, 300, 16384, 320);
    padcopy_f32<<<dim3((320 * 1024 + 255) / 256), blk, 0, stream>>>(Wr1, WPf, 300, 1024, 320, 1024);
    // TR = XP @ WP   (16384,320)@(320,1024)
    gemm_split<<<dim3(8, 128, 1), blk, 0, stream>>>(XPf, 0, 320, WPf, 0, 1024,
        TRf, 0, 1024, nullptr, 0, 0, nullptr, 320, 0);
    // HR = relu(Ar@TR + TR)  batched 8
    gemm_split<<<dim3(8, 16, 8), blk, 0, stream>>>(Ar, 2048LL * 2048, 2048, TRf, 2048LL * 1024, 1024,
        HRf, 2048LL * 1024, 1024, TRf, 2048LL * 1024, 1024, nullptr, 2048, 1);
    // T2R = HR @ Wr2  (16384,1024)@(1024,512)
    gemm_split<<<dim3(4, 128, 1), blk, 0, stream>>>(HRf, 0, 1024, Wr2, 0, 512,
        T2Rf, 0, 512, nullptr, 0, 0, nullptr, 1024, 0);
    // GR = relu(Ar@T2R + T2R)  batched 8
    gemm_split<<<dim3(4, 16, 8), blk, 0, stream>>>(Ar, 2048LL * 2048, 2048, T2Rf, 2048LL * 512, 512,
        GRf, 2048LL * 512, 512, T2Rf, 2048LL * 512, 512, nullptr, 2048, 1);
    // q/k/v = GR @ W? + b?  (16384,512)@(512,512) -> fp32
    gemm_split<<<dim3(4, 128, 1), blk, 0, stream>>>(GRf, 0, 512, Wq, 0, 512,
        qF, 0, 512, nullptr, 0, 0, bq, 512, 0);
    gemm_split<<<dim3(4, 128, 1), blk, 0, stream>>>(GRf, 0, 512, Wk, 0, 512,
        kF, 0, 512, nullptr, 0, 0, bk, 512, 0);
    gemm_split<<<dim3(4, 128, 1), blk, 0, stream>>>(GRf, 0, 512, Wv, 0, 512,
        vF, 0, 512, nullptr, 0, 0, bv, 512, 0);
    // fused attention + query-mean -> ABAR bf16 (4096,512)
    attn_kernel<<<dim3(2048, 2), blk, 0, stream>>>(qF, kF, vF, ABAR);

    // ---- o-branch (bf16) ----
    cvt(srco, srcoB, 4194304);
    cvt(Ao, AoB, 2097152);
    cvt(Wo1, Wo1B, 1048576);
    cvt(Wo2, Wo2B, 524288);
    cvt(We, WeB, 524288);
    cvt(Wp, WpB, 262144);
    // TO = srco @ Wo1  (4096,1024)@(1024,1024)
    gemm_bf16<<<dim3(8, 32, 1), blk, 0, stream>>>(srcoB, 0, 1024, Wo1B, 0, 1024,
        TO, 0, 1024, nullptr, 0, 0, nullptr, 1024, 0, 0);
    // HO = relu(Ao@TO + TO)  batched 8
    gemm_bf16<<<dim3(8, 4, 8), blk, 0, stream>>>(AoB, 512LL * 512, 512, TO, 512LL * 1024, 1024,
        HO, 512LL * 1024, 1024, TO, 512LL * 1024, 1024, nullptr, 512, 1, 0);
    // T2O = HO @ Wo2  (4096,1024)@(1024,512)
    gemm_bf16<<<dim3(4, 32, 1), blk, 0, stream>>>(HO, 0, 1024, Wo2B, 0, 512,
        T2O, 0, 512, nullptr, 0, 0, nullptr, 1024, 0, 0);
    // g_o = relu(Ao@T2O + T2O) -> CAT right half
    gemm_bf16<<<dim3(4, 4, 8), blk, 0, stream>>>(AoB, 512LL * 512, 512, T2O, 512LL * 512, 512,
        (void*)(CAT + 512), 512LL * 1024, 1024, T2O, 512LL * 512, 512, nullptr, 512, 1, 0);
    // P = ABAR @ Wp + bp -> CAT left half
    gemm_bf16<<<dim3(4, 32, 1), blk, 0, stream>>>(ABAR, 0, 512, WpB, 0, 512,
        CAT, 0, 1024, nullptr, 0, 0, bp, 512, 0, 0);
    // out = CAT @ We + be  -> fp32
    gemm_bf16<<<dim3(4, 32, 1), blk, 0, stream>>>(CAT, 0, 1024, WeB, 0, 512,
        out, 0, 512, nullptr, 0, 0, be, 1024, 0, 1);
}

// Round 4
// 1203.149 us; speedup vs baseline: 1.5775x; 1.5775x over previous
//
#include <hip/hip_runtime.h>
#include <hip/hip_bf16.h>

// ---------------------------------------------------------------------------
// B=8, NT=32, NO=8, C=512, VD=1024, RD=300; No=512, Nr=2048.
// Inputs fp32. r-chain: split-bf16 MFMA (hi/lo planes in LDS, ~fp32 accurate),
// fp32 intermediates, with associativity refactor (Ar+I)@XP@WP.
// o-branch + epilogue: plain bf16 MFMA. Output fp32.
// ---------------------------------------------------------------------------

typedef __attribute__((ext_vector_type(4))) float f32x4;
typedef __attribute__((ext_vector_type(8))) short bf16x8s;

#define TILE 128
#define BKK 32
#define LDSS 40  // bf16 LDS row stride (32+8)

__device__ inline void split2(float a, float b, unsigned& h, unsigned& l) {
    __hip_bfloat16 ha = __float2bfloat16(a), hb = __float2bfloat16(b);
    float ra = __bfloat162float(ha), rb = __bfloat162float(hb);
    __hip_bfloat16 la = __float2bfloat16(a - ra), lb = __float2bfloat16(b - rb);
    unsigned short uha = *(unsigned short*)&ha, uhb = *(unsigned short*)&hb;
    unsigned short ula = *(unsigned short*)&la, ulb = *(unsigned short*)&lb;
    h = (unsigned)uha | ((unsigned)uhb << 16);
    l = (unsigned)ula | ((unsigned)ulb << 16);
}

// ---------------- split-precision GEMM v2 -----------------------------------
// D = act(A@B + addN + addT^T + bias); A:(batch,M,K) fp32; BT:(batch,N,K) fp32
// (B transposed). Stages hi/lo bf16 planes in LDS; 3 MFMAs (hh+hl+lh).
__global__ __launch_bounds__(256) void gemm_split2(
    const float* __restrict__ A, long long sA, int lda,
    const float* __restrict__ BT, long long sBT, int ldbt,
    float* __restrict__ D, long long sD, int ldd,
    const float* __restrict__ addN, long long sAddN, int ldaddN,
    const float* __restrict__ addT, long long sAddT, int ldaddT,
    const float* __restrict__ bias,
    int K, int relu)
{
    __shared__ __hip_bfloat16 Ah[TILE * LDSS], Al[TILE * LDSS];
    __shared__ __hip_bfloat16 Bh[TILE * LDSS], Bl[TILE * LDSS]; // Bh[n][k]

    const int tid  = threadIdx.x;
    const int lane = tid & 63;
    const int wave = tid >> 6;
    const int wm   = (wave >> 1) * 64;
    const int wn   = (wave & 1) * 64;
    const int row0 = blockIdx.y * TILE;
    const int col0 = blockIdx.x * TILE;
    const int b    = blockIdx.z;

    const float* Ab = A  + (size_t)b * sA;
    const float* Bb = BT + (size_t)b * sBT;

    f32x4 acc[4][4];
#pragma unroll
    for (int i = 0; i < 4; ++i)
#pragma unroll
        for (int j = 0; j < 4; ++j) acc[i][j] = (f32x4){0.f, 0.f, 0.f, 0.f};

    const int quad = lane >> 4;
    const int l16  = lane & 15;

    for (int k0 = 0; k0 < K; k0 += BKK) {
        __syncthreads();
#pragma unroll
        for (int it = 0; it < 2; ++it) { // A tile 128x32: 8 floats per task
            int task = tid + it * 256;
            int m = task >> 2, kq = task & 3;
            const float* ap = Ab + (size_t)(row0 + m) * lda + k0 + kq * 8;
            float4 v0 = *(const float4*)ap;
            float4 v1 = *(const float4*)(ap + 4);
            uint4 H, L;
            split2(v0.x, v0.y, H.x, L.x); split2(v0.z, v0.w, H.y, L.y);
            split2(v1.x, v1.y, H.z, L.z); split2(v1.z, v1.w, H.w, L.w);
            *(uint4*)(&Ah[m * LDSS + kq * 8]) = H;
            *(uint4*)(&Al[m * LDSS + kq * 8]) = L;
        }
#pragma unroll
        for (int it = 0; it < 2; ++it) { // BT tile 128x32 (n-major, same pattern)
            int task = tid + it * 256;
            int n = task >> 2, kq = task & 3;
            const float* bp = Bb + (size_t)(col0 + n) * ldbt + k0 + kq * 8;
            float4 v0 = *(const float4*)bp;
            float4 v1 = *(const float4*)(bp + 4);
            uint4 H, L;
            split2(v0.x, v0.y, H.x, L.x); split2(v0.z, v0.w, H.y, L.y);
            split2(v1.x, v1.y, H.z, L.z); split2(v1.z, v1.w, H.w, L.w);
            *(uint4*)(&Bh[n * LDSS + kq * 8]) = H;
            *(uint4*)(&Bl[n * LDSS + kq * 8]) = L;
        }
        __syncthreads();

        bf16x8s ah[4], al[4], bh[4], bl[4];
#pragma unroll
        for (int mt = 0; mt < 4; ++mt) {
            int r = (wm + mt * 16 + l16) * LDSS + quad * 8;
            ah[mt] = *(const bf16x8s*)(&Ah[r]);
            al[mt] = *(const bf16x8s*)(&Al[r]);
        }
#pragma unroll
        for (int nt = 0; nt < 4; ++nt) {
            int r = (wn + nt * 16 + l16) * LDSS + quad * 8;
            bh[nt] = *(const bf16x8s*)(&Bh[r]);
            bl[nt] = *(const bf16x8s*)(&Bl[r]);
        }
#pragma unroll
        for (int mt = 0; mt < 4; ++mt)
#pragma unroll
            for (int nt = 0; nt < 4; ++nt) {
                acc[mt][nt] = __builtin_amdgcn_mfma_f32_16x16x32_bf16(ah[mt], bh[nt], acc[mt][nt], 0, 0, 0);
                acc[mt][nt] = __builtin_amdgcn_mfma_f32_16x16x32_bf16(ah[mt], bl[nt], acc[mt][nt], 0, 0, 0);
                acc[mt][nt] = __builtin_amdgcn_mfma_f32_16x16x32_bf16(al[mt], bh[nt], acc[mt][nt], 0, 0, 0);
            }
    }

    float* Db = D + (size_t)b * sD;
    const float* AddN = addN ? addN + (size_t)b * sAddN : nullptr;
    const float* AddT = addT ? addT + (size_t)b * sAddT : nullptr;
#pragma unroll
    for (int mt = 0; mt < 4; ++mt)
#pragma unroll
        for (int nt = 0; nt < 4; ++nt)
#pragma unroll
            for (int r = 0; r < 4; ++r) {
                int m = row0 + wm + mt * 16 + quad * 4 + r;
                int n = col0 + wn + nt * 16 + l16;
                float v = acc[mt][nt][r];
                if (AddN) v += AddN[(size_t)m * ldaddN + n];
                if (AddT) v += AddT[(size_t)n * ldaddT + m];
                if (bias) v += bias[n];
                if (relu && v < 0.f) v = 0.f;
                Db[(size_t)m * ldd + n] = v;
            }
}

// ---------------- tiled fp32 transpose with zero-pad ------------------------
// Logical padded src S'(Rp x Cp): S'[r][c] = (r<R && c<C) ? src[r*C+c] : 0.
// dst = S'^T  (Cp x Rp). Batched: src += bat*R*C (dense), dst += bat*Cp*Rp.
// Rp, Cp multiples of 64. Grid: (Cp/64, Rp/64, batch), block 256.
__global__ __launch_bounds__(256) void padtrans(
    const float* __restrict__ src, float* __restrict__ dst,
    int R, int C, int Rp, int Cp)
{
    __shared__ float T[64][65];
    const int t = threadIdx.x;
    const int tr = t >> 4, tc = t & 15;
    const int c0 = blockIdx.x * 64, r0 = blockIdx.y * 64;
    const size_t bat = blockIdx.z;
    const float* sb = src + bat * (size_t)R * C;
    float* db = dst + bat * (size_t)Cp * Rp;

#pragma unroll
    for (int i = 0; i < 4; ++i) {
        int rr = tr + i * 16;
        int gr = r0 + rr;
        float v0 = 0.f, v1 = 0.f, v2 = 0.f, v3 = 0.f;
        if (gr < R) {
            int c = c0 + tc * 4;
            const float* s = sb + (size_t)gr * C + c;
            if (c + 0 < C) v0 = s[0];
            if (c + 1 < C) v1 = s[1];
            if (c + 2 < C) v2 = s[2];
            if (c + 3 < C) v3 = s[3];
        }
        T[rr][tc * 4 + 0] = v0; T[rr][tc * 4 + 1] = v1;
        T[rr][tc * 4 + 2] = v2; T[rr][tc * 4 + 3] = v3;
    }
    __syncthreads();
#pragma unroll
    for (int i = 0; i < 4; ++i) {
        int cc = tr + i * 16;
        float4 v = { T[tc * 4 + 0][cc], T[tc * 4 + 1][cc],
                     T[tc * 4 + 2][cc], T[tc * 4 + 3][cc] };
        *(float4*)(db + (size_t)(c0 + cc) * Rp + r0 + tc * 4) = v;
    }
}

// ---------------- plain bf16 GEMM (o-branch / epilogue) ---------------------
__global__ __launch_bounds__(256) void gemm_bf16(
    const __hip_bfloat16* __restrict__ A, long long sA, int lda,
    const __hip_bfloat16* __restrict__ B, long long sB, int ldb,
    void* __restrict__ D, long long sD, int ldd,
    const __hip_bfloat16* __restrict__ addsrc, long long sAdd, int ldadd,
    const float* __restrict__ bias,
    int K, int relu, int outF32)
{
    __shared__ __hip_bfloat16 As[TILE * LDSS];
    __shared__ __hip_bfloat16 Bs[TILE * LDSS]; // transposed: Bs[n][k]

    const int tid  = threadIdx.x;
    const int lane = tid & 63;
    const int wave = tid >> 6;
    const int wm   = (wave >> 1) * 64;
    const int wn   = (wave & 1) * 64;
    const int row0 = blockIdx.y * TILE;
    const int col0 = blockIdx.x * TILE;
    const int b    = blockIdx.z;

    const __hip_bfloat16* Ab = A + (size_t)b * sA;
    const __hip_bfloat16* Bb = B + (size_t)b * sB;

    f32x4 acc[4][4];
#pragma unroll
    for (int i = 0; i < 4; ++i)
#pragma unroll
        for (int j = 0; j < 4; ++j) acc[i][j] = (f32x4){0.f, 0.f, 0.f, 0.f};

    const int quad = lane >> 4;
    const int l16  = lane & 15;

    for (int k0 = 0; k0 < K; k0 += BKK) {
        __syncthreads();
#pragma unroll
        for (int it = 0; it < 2; ++it) {
            int task = tid + it * 256;
            int m = task >> 2, kq = task & 3;
            uint4 val = *(const uint4*)(Ab + (size_t)(row0 + m) * lda + k0 + kq * 8);
            *(uint4*)(&As[m * LDSS + kq * 8]) = val;
        }
#pragma unroll
        for (int it = 0; it < 2; ++it) {
            int task = tid + it * 256;
            int kk = task >> 4, n8 = task & 15;
            uint4 val = *(const uint4*)(Bb + (size_t)(k0 + kk) * ldb + col0 + n8 * 8);
            const __hip_bfloat16* v16 = (const __hip_bfloat16*)&val;
#pragma unroll
            for (int u = 0; u < 8; ++u)
                Bs[(n8 * 8 + u) * LDSS + kk] = v16[u];
        }
        __syncthreads();

        bf16x8s afrag[4], bfrag[4];
#pragma unroll
        for (int mt = 0; mt < 4; ++mt)
            afrag[mt] = *(const bf16x8s*)(&As[(wm + mt * 16 + l16) * LDSS + quad * 8]);
#pragma unroll
        for (int nt = 0; nt < 4; ++nt)
            bfrag[nt] = *(const bf16x8s*)(&Bs[(wn + nt * 16 + l16) * LDSS + quad * 8]);
#pragma unroll
        for (int mt = 0; mt < 4; ++mt)
#pragma unroll
            for (int nt = 0; nt < 4; ++nt)
                acc[mt][nt] = __builtin_amdgcn_mfma_f32_16x16x32_bf16(
                    afrag[mt], bfrag[nt], acc[mt][nt], 0, 0, 0);
    }

    __hip_bfloat16* Db16 = (__hip_bfloat16*)D + (size_t)b * sD;
    float*          DbF  = (float*)D + (size_t)b * sD;
    const __hip_bfloat16* Addb = addsrc ? addsrc + (size_t)b * sAdd : nullptr;
#pragma unroll
    for (int mt = 0; mt < 4; ++mt)
#pragma unroll
        for (int nt = 0; nt < 4; ++nt)
#pragma unroll
            for (int r = 0; r < 4; ++r) {
                int m = row0 + wm + mt * 16 + quad * 4 + r;
                int n = col0 + wn + nt * 16 + l16;
                float v = acc[mt][nt][r];
                if (Addb) v += __bfloat162float(Addb[(size_t)m * ldadd + n]);
                if (bias) v += bias[n];
                if (relu && v < 0.f) v = 0.f;
                if (outF32) DbF[(size_t)m * ldd + n] = v;
                else        Db16[(size_t)m * ldd + n] = __float2bfloat16(v);
            }
}

// fp32 -> bf16 converter (n divisible by 4)
__global__ void convert_kernel(const float* __restrict__ src,
                               __hip_bfloat16* __restrict__ dst, int n4)
{
    int i = blockIdx.x * blockDim.x + threadIdx.x;
    if (i >= n4) return;
    float4 v = ((const float4*)src)[i];
    __hip_bfloat16 t0 = __float2bfloat16(v.x), t1 = __float2bfloat16(v.y);
    __hip_bfloat16 t2 = __float2bfloat16(v.z), t3 = __float2bfloat16(v.w);
    ushort4 o = { *(unsigned short*)&t0, *(unsigned short*)&t1,
                  *(unsigned short*)&t2, *(unsigned short*)&t3 };
    ((ushort4*)dst)[i] = o;
}

// ---------------- fused segment attention + query-mean (fp32 q/k/v) ---------
__global__ __launch_bounds__(256) void attn_kernel(
    const float* __restrict__ q,
    const float* __restrict__ k,
    const float* __restrict__ v,
    __hip_bfloat16* __restrict__ abar)
{
    __shared__ float qs[8][512], ks[8][512], vs[8][512];
    __shared__ float sc[4][8][8];
    __shared__ float wb[4][8];

    const int tid  = threadIdx.x;
    const int mode = blockIdx.y;
    const int g    = blockIdx.x >> 3;
    const int idx  = blockIdx.x & 7;
    const int rowBase = g * 64;

    for (int t = tid; t < 512; t += 256) {
        int p = t >> 6, c8 = (t & 63) * 8;
        int row = (mode == 0) ? (rowBase + idx * 8 + p) : (rowBase + p * 8 + idx);
        const float* qp = q + (size_t)row * 512 + c8;
        const float* kp = k + (size_t)row * 512 + c8;
        const float* vp = v + (size_t)row * 512 + c8;
        *(float4*)(&qs[p][c8])     = *(const float4*)(qp);
        *(float4*)(&qs[p][c8 + 4]) = *(const float4*)(qp + 4);
        *(float4*)(&ks[p][c8])     = *(const float4*)(kp);
        *(float4*)(&ks[p][c8 + 4]) = *(const float4*)(kp + 4);
        *(float4*)(&vs[p][c8])     = *(const float4*)(vp);
        *(float4*)(&vs[p][c8 + 4]) = *(const float4*)(vp + 4);
    }
    __syncthreads();

    {
        int h = tid >> 6, l = tid & 63;
        int i = l >> 3, j = l & 7;
        const float* qrow = &qs[i][h * 128];
        const float* krow = &ks[j][h * 128];
        float s = 0.f;
#pragma unroll
        for (int d = 0; d < 128; d += 4) {
            float4 qa = *(const float4*)(qrow + d);
            float4 kb = *(const float4*)(krow + d);
            s += qa.x * kb.x + qa.y * kb.y + qa.z * kb.z + qa.w * kb.w;
        }
        sc[h][i][j] = s * 0.08838834764831845f;
    }
    __syncthreads();

    if (tid < 32) {
        int h = tid >> 3, i = tid & 7;
        float mx = -1e30f;
#pragma unroll
        for (int j = 0; j < 8; ++j) mx = fmaxf(mx, sc[h][i][j]);
        float e[8], sum = 0.f;
#pragma unroll
        for (int j = 0; j < 8; ++j) { e[j] = __expf(sc[h][i][j] - mx); sum += e[j]; }
        float inv = 1.f / sum;
#pragma unroll
        for (int j = 0; j < 8; ++j) sc[h][i][j] = e[j] * inv;
    }
    __syncthreads();

    if (tid < 32) {
        int h = tid >> 3, j = tid & 7;
        float s = 0.f;
#pragma unroll
        for (int i = 0; i < 8; ++i) s += sc[h][i][j];
        wb[h][j] = s * 0.125f;
    }
    __syncthreads();

    {
        int orow = g * 16 + mode * 8 + idx;
        for (int c = tid; c < 512; c += 256) {
            int h = c >> 7;
            float o = 0.f;
#pragma unroll
            for (int j = 0; j < 8; ++j) o += wb[h][j] * vs[j][c];
            abar[(size_t)orow * 512 + c] = __float2bfloat16(o);
        }
    }
}

// ---------------------------------------------------------------------------

extern "C" void kernel_launch(void* const* d_in, const int* in_sizes, int n_in,
                              void* d_out, int out_size, void* d_ws, size_t ws_size,
                              hipStream_t stream)
{
    const float* Ao   = (const float*)d_in[0];   // (8,512,512)
    const float* srco = (const float*)d_in[1];   // (4096,1024)
    const float* Ar   = (const float*)d_in[2];   // (8,2048,2048)
    const float* srcr = (const float*)d_in[3];   // (16384,300)
    const float* Wo1  = (const float*)d_in[4];   // (1024,1024)
    const float* Wo2  = (const float*)d_in[5];   // (1024,512)
    const float* Wr1  = (const float*)d_in[6];   // (300,1024)
    const float* Wr2  = (const float*)d_in[7];   // (1024,512)
    const float* Wq   = (const float*)d_in[8];
    const float* bq   = (const float*)d_in[9];
    const float* Wk   = (const float*)d_in[10];
    const float* bk   = (const float*)d_in[11];
    const float* Wv   = (const float*)d_in[12];
    const float* bv   = (const float*)d_in[13];
    const float* Wp   = (const float*)d_in[14];
    const float* bp   = (const float*)d_in[15];
    const float* We   = (const float*)d_in[16];  // (1024,512)
    const float* be   = (const float*)d_in[17];
    float* out = (float*)d_out;                  // (4096,512) fp32

    char* ws = (char*)d_ws;
    // Layout (all fp32 unless noted), lifetime-safe reuse:
    // R0 (0, 67.1M):      HRf -> later qF(+0), kF(+33.55M)
    // R1 (67.1M, 33.5M):  T2Rf -> later vF
    // R2 (100.7M, 33.5M): Uf, then T2RT, then o-branch bf16 pool (48M, spans R3)
    // R3 (134.2M, 33.5M): GRf
    // R4 (167.8M, 25.2M): XPT -> later ABAR (bf16, 4.2M)
    // R5 (193.0M, 6.6M):  transposed weights
    const size_t R0 = 0;
    const size_t R1 = 67108864;
    const size_t R2 = 100663296;
    const size_t R3 = 134217728;
    const size_t R4 = 167772160;
    const size_t R5 = 192937984;

    float* HRf  = (float*)(ws + R0);
    float* qF   = (float*)(ws + R0);
    float* kF   = (float*)(ws + R0 + 33554432);
    float* T2Rf = (float*)(ws + R1);
    float* vF   = (float*)(ws + R1);
    float* Uf   = (float*)(ws + R2);
    float* T2RT = (float*)(ws + R2);
    float* GRf  = (float*)(ws + R3);
    float* XPT  = (float*)(ws + R4);
    __hip_bfloat16* ABAR = (__hip_bfloat16*)(ws + R4);
    float* WPT  = (float*)(ws + R5);                 // (1024,320)
    float* Wr2T = (float*)(ws + R5 + 1310720);       // (512,1024)
    float* WqT  = (float*)(ws + R5 + 3407872);       // (512,512)
    float* WkT  = (float*)(ws + R5 + 4456448);
    float* WvT  = (float*)(ws + R5 + 5505024);

    // o-branch bf16 pool at R2 (valid after attn inputs consumed)
    __hip_bfloat16* TO    = (__hip_bfloat16*)(ws + R2 + 0);
    __hip_bfloat16* HO    = (__hip_bfloat16*)(ws + R2 + 8388608);
    __hip_bfloat16* T2O   = (__hip_bfloat16*)(ws + R2 + 16777216);
    __hip_bfloat16* CAT   = (__hip_bfloat16*)(ws + R2 + 20971520);
    __hip_bfloat16* srcoB = (__hip_bfloat16*)(ws + R2 + 29360128);
    __hip_bfloat16* AoB   = (__hip_bfloat16*)(ws + R2 + 37748736);
    __hip_bfloat16* Wo1B  = (__hip_bfloat16*)(ws + R2 + 41943040);
    __hip_bfloat16* Wo2B  = (__hip_bfloat16*)(ws + R2 + 44040192);
    __hip_bfloat16* WeB   = (__hip_bfloat16*)(ws + R2 + 45088768);
    __hip_bfloat16* WpB   = (__hip_bfloat16*)(ws + R2 + 46137344);

    dim3 blk(256);
    auto cvt = [&](const float* s, __hip_bfloat16* d, int n) {
        convert_kernel<<<dim3((n / 4 + 255) / 256), blk, 0, stream>>>(s, d, n / 4);
    };

    // ---- transposes ----
    // XPT (8,384,2048) from srcr (16384,300) viewed (8,2048,300)
    padtrans<<<dim3(6, 32, 8), blk, 0, stream>>>(srcr, XPT, 2048, 300, 2048, 384);
    // WPT (1024,320) from Wr1 (300,1024)
    padtrans<<<dim3(16, 5, 1), blk, 0, stream>>>(Wr1, WPT, 300, 1024, 320, 1024);
    // Wr2T (512,1024), WqT/WkT/WvT (512,512)
    padtrans<<<dim3(8, 16, 1), blk, 0, stream>>>(Wr2, Wr2T, 1024, 512, 1024, 512);
    padtrans<<<dim3(8, 8, 1), blk, 0, stream>>>(Wq, WqT, 512, 512, 512, 512);
    padtrans<<<dim3(8, 8, 1), blk, 0, stream>>>(Wk, WkT, 512, 512, 512, 512);
    padtrans<<<dim3(8, 8, 1), blk, 0, stream>>>(Wv, WvT, 512, 512, 512, 512);

    // ---- r-branch (split precision) ----
    // U = Ar@XP + XP   (8: 2048x2048 @ 2048x384), BT=XPT, addT=XPT
    gemm_split2<<<dim3(3, 16, 8), blk, 0, stream>>>(
        Ar, 2048LL * 2048, 2048, XPT, 384LL * 2048, 2048,
        Uf, 2048LL * 384, 384, nullptr, 0, 0, XPT, 384LL * 2048, 2048,
        nullptr, 2048, 0);
    // HR = relu(U@WP)  (16384x320 @ 320x1024), BT=WPT
    gemm_split2<<<dim3(8, 128, 1), blk, 0, stream>>>(
        Uf, 0, 384, WPT, 0, 320,
        HRf, 0, 1024, nullptr, 0, 0, nullptr, 0, 0,
        nullptr, 320, 1);
    // T2R = HR@Wr2  (16384x1024 @ 1024x512), BT=Wr2T
    gemm_split2<<<dim3(4, 128, 1), blk, 0, stream>>>(
        HRf, 0, 1024, Wr2T, 0, 1024,
        T2Rf, 0, 512, nullptr, 0, 0, nullptr, 0, 0,
        nullptr, 1024, 0);
    // T2RT (8,512,2048) from T2Rf viewed (8,2048,512)
    padtrans<<<dim3(8, 32, 8), blk, 0, stream>>>(T2Rf, T2RT, 2048, 512, 2048, 512);
    // GR = relu(Ar@T2R + T2R)  (8: 2048x2048 @ 2048x512), BT=T2RT, addN=T2Rf
    gemm_split2<<<dim3(4, 16, 8), blk, 0, stream>>>(
        Ar, 2048LL * 2048, 2048, T2RT, 512LL * 2048, 2048,
        GRf, 2048LL * 512, 512, T2Rf, 2048LL * 512, 512, nullptr, 0, 0,
        nullptr, 2048, 1);
    // q/k/v = GR @ W? + b?  (16384x512 @ 512x512)
    gemm_split2<<<dim3(4, 128, 1), blk, 0, stream>>>(
        GRf, 0, 512, WqT, 0, 512, qF, 0, 512,
        nullptr, 0, 0, nullptr, 0, 0, bq, 512, 0);
    gemm_split2<<<dim3(4, 128, 1), blk, 0, stream>>>(
        GRf, 0, 512, WkT, 0, 512, kF, 0, 512,
        nullptr, 0, 0, nullptr, 0, 0, bk, 512, 0);
    gemm_split2<<<dim3(4, 128, 1), blk, 0, stream>>>(
        GRf, 0, 512, WvT, 0, 512, vF, 0, 512,
        nullptr, 0, 0, nullptr, 0, 0, bv, 512, 0);
    // fused attention + query-mean -> ABAR bf16 (4096,512); XPT dead
    attn_kernel<<<dim3(2048, 2), blk, 0, stream>>>(qF, kF, vF, ABAR);

    // ---- o-branch (bf16) ----
    cvt(srco, srcoB, 4194304);
    cvt(Ao, AoB, 2097152);
    cvt(Wo1, Wo1B, 1048576);
    cvt(Wo2, Wo2B, 524288);
    cvt(We, WeB, 524288);
    cvt(Wp, WpB, 262144);
    // TO = srco @ Wo1  (4096,1024)@(1024,1024)
    gemm_bf16<<<dim3(8, 32, 1), blk, 0, stream>>>(srcoB, 0, 1024, Wo1B, 0, 1024,
        TO, 0, 1024, nullptr, 0, 0, nullptr, 1024, 0, 0);
    // HO = relu(Ao@TO + TO)  batched 8
    gemm_bf16<<<dim3(8, 4, 8), blk, 0, stream>>>(AoB, 512LL * 512, 512, TO, 512LL * 1024, 1024,
        HO, 512LL * 1024, 1024, TO, 512LL * 1024, 1024, nullptr, 512, 1, 0);
    // T2O = HO @ Wo2  (4096,1024)@(1024,512)
    gemm_bf16<<<dim3(4, 32, 1), blk, 0, stream>>>(HO, 0, 1024, Wo2B, 0, 512,
        T2O, 0, 512, nullptr, 0, 0, nullptr, 1024, 0, 0);
    // g_o = relu(Ao@T2O + T2O) -> CAT right half
    gemm_bf16<<<dim3(4, 4, 8), blk, 0, stream>>>(AoB, 512LL * 512, 512, T2O, 512LL * 512, 512,
        (void*)(CAT + 512), 512LL * 1024, 1024, T2O, 512LL * 512, 512, nullptr, 512, 1, 0);
    // P = ABAR @ Wp + bp -> CAT left half
    gemm_bf16<<<dim3(4, 32, 1), blk, 0, stream>>>(ABAR, 0, 512, WpB, 0, 512,
        CAT, 0, 1024, nullptr, 0, 0, bp, 512, 0, 0);
    // out = CAT @ We + be  -> fp32
    gemm_bf16<<<dim3(4, 32, 1), blk, 0, stream>>>(CAT, 0, 1024, WeB, 0, 512,
        out, 0, 512, nullptr, 0, 0, be, 1024, 0, 1);
}